// Round 1
// baseline (417.934 us; speedup 1.0000x reference)
//
#include <hip/hip_runtime.h>

typedef short short8 __attribute__((ext_vector_type(8)));
typedef float f32x4 __attribute__((ext_vector_type(4)));

#define SQ   1024
#define DIN  768
#define NH   12
#define DH   64

static __device__ __forceinline__ ushort f2bf(float f) {
  union { float f; unsigned u; } v; v.f = f;
  unsigned u = v.u;
  unsigned r = (u + 0x7FFFu + ((u >> 16) & 1u)) >> 16;
  return (ushort)r;
}

// ---------------------------------------------------------------- prep: x -> bf16
__global__ __launch_bounds__(256) void k_convert_x(const float* __restrict__ x,
                                                   ushort* __restrict__ xb) {
  int i = (blockIdx.x * 256 + threadIdx.x) * 4;
  float4 v = *reinterpret_cast<const float4*>(x + i);
  ushort4 o;
  o.x = f2bf(v.x); o.y = f2bf(v.y); o.z = f2bf(v.z); o.w = f2bf(v.w);
  *reinterpret_cast<ushort4*>(xb + i) = o;
}

// ------------------------------------------- prep: W[h][d][e] -> Wt[m*12+h][e][d] bf16
__global__ __launch_bounds__(256) void k_prep_w(const float* __restrict__ Wq,
                                                const float* __restrict__ Wk,
                                                const float* __restrict__ Wv,
                                                ushort* __restrict__ wt) {
  __shared__ ushort tile[64][65];
  const int mh = blockIdx.x;            // m*12 + h
  const int m = mh / 12, h = mh % 12;
  const float* W = (m == 0 ? Wq : (m == 1 ? Wk : Wv)) + h * DIN * DH;
  ushort* outp = wt + mh * DH * DIN;
  for (int d0 = 0; d0 < DIN; d0 += 64) {
    __syncthreads();
    #pragma unroll
    for (int p = 0; p < 16; ++p) {
      int idx = p * 256 + threadIdx.x;
      int d = idx >> 6, e = idx & 63;
      tile[d][e] = f2bf(W[(d0 + d) * DH + e]);
    }
    __syncthreads();
    #pragma unroll
    for (int p = 0; p < 16; ++p) {
      int idx = p * 256 + threadIdx.x;
      int e = idx >> 6, d = idx & 63;
      outp[e * DIN + d0 + d] = tile[d][e];
    }
  }
}

// ------------------------------------------------- QKV projection GEMM (bf16 MFMA)
// grid: (64 row-tiles of 128, 36 = m*12+h); block 256 (4 waves, each 32x64)
__global__ __launch_bounds__(256) void k_proj(const ushort* __restrict__ xb,
                                              const ushort* __restrict__ wt,
                                              ushort* __restrict__ qo,
                                              ushort* __restrict__ ko,
                                              ushort* __restrict__ vto) {
  const int mh = blockIdx.y;
  const int m = mh / 12, h = mh % 12;
  const int w = threadIdx.x >> 6, lane = threadIdx.x & 63;
  const int lr = lane & 15, lg = lane >> 4;
  const int srow = blockIdx.x * 128 + w * 32;   // flat row base (b*1024+s), wave-local
  const ushort* wbase = wt + mh * (DH * DIN);

  f32x4 acc[2][4];
  #pragma unroll
  for (int i = 0; i < 2; ++i)
    #pragma unroll
    for (int j = 0; j < 4; ++j) acc[i][j] = (f32x4){0.f, 0.f, 0.f, 0.f};

  #pragma unroll 2
  for (int k0 = 0; k0 < DIN; k0 += 32) {
    short8 a[2], b[4];
    #pragma unroll
    for (int mi = 0; mi < 2; ++mi)
      a[mi] = *reinterpret_cast<const short8*>(xb + (size_t)(srow + mi * 16 + lr) * DIN + k0 + lg * 8);
    #pragma unroll
    for (int ci = 0; ci < 4; ++ci)
      b[ci] = *reinterpret_cast<const short8*>(wbase + (size_t)(ci * 16 + lr) * DIN + k0 + lg * 8);
    #pragma unroll
    for (int mi = 0; mi < 2; ++mi)
      #pragma unroll
      for (int ci = 0; ci < 4; ++ci)
        acc[mi][ci] = __builtin_amdgcn_mfma_f32_16x16x32_bf16(a[mi], b[ci], acc[mi][ci], 0, 0, 0);
  }

  const int bidx = srow >> 10;       // batch
  const int sl0  = srow & 1023;      // s within batch
  const int bh   = bidx * 12 + h;
  #pragma unroll
  for (int mi = 0; mi < 2; ++mi)
    #pragma unroll
    for (int ci = 0; ci < 4; ++ci)
      #pragma unroll
      for (int r = 0; r < 4; ++r) {
        int sl = sl0 + mi * 16 + lg * 4 + r;
        int e  = ci * 16 + lr;
        ushort val = f2bf(acc[mi][ci][r]);
        if (m == 2) {
          vto[((size_t)bh * DH + e) * SQ + sl] = val;           // V transposed [bh][e][s]
        } else {
          ushort* dst = (m == 0) ? qo : ko;
          dst[((size_t)bh * SQ + sl) * DH + e] = val;           // [bh][s][e]
        }
      }
}

// ------------------------------------------------- fused causal flash attention
// grid: (8 q-tiles of 128, 96 = b*12+h); block 256; 4 independent waves (32 q-rows each)
__global__ __launch_bounds__(256) void k_attn(const ushort* __restrict__ qi,
                                              const ushort* __restrict__ ki,
                                              const ushort* __restrict__ vti,
                                              float* __restrict__ out) {
  __shared__ __align__(16) ushort plds[4][32][72];   // per-wave P tile, padded (72) for b128 reads
  const int bh = blockIdx.y;
  const int b = bh / 12, h = bh % 12;
  const int w = threadIdx.x >> 6, lane = threadIdx.x & 63;
  const int lr = lane & 15, lg = lane >> 4;
  const int q0 = blockIdx.x * 128 + w * 32;          // s_local base for this wave
  const ushort* qb = qi  + (size_t)bh * SQ * DH;
  const ushort* kb = ki  + (size_t)bh * SQ * DH;
  const ushort* vb = vti + (size_t)bh * DH * SQ;

  short8 aq[2][2];
  #pragma unroll
  for (int mi = 0; mi < 2; ++mi)
    #pragma unroll
    for (int x2 = 0; x2 < 2; ++x2)
      aq[mi][x2] = *reinterpret_cast<const short8*>(qb + (size_t)(q0 + mi * 16 + lr) * DH + x2 * 32 + lg * 8);

  f32x4 oacc[2][4];
  float mrow[2][4], lsum[2][4];
  #pragma unroll
  for (int mi = 0; mi < 2; ++mi) {
    #pragma unroll
    for (int ci = 0; ci < 4; ++ci) oacc[mi][ci] = (f32x4){0.f, 0.f, 0.f, 0.f};
    #pragma unroll
    for (int r = 0; r < 4; ++r) { mrow[mi][r] = -1e30f; lsum[mi][r] = 0.f; }
  }

  const int nt = (q0 + 31) / 64 + 1;
  for (int t = 0; t < nt; ++t) {
    const int kv0 = t * 64;
    // ---- S = Q K^T * scale, causal mask
    short8 bk[4][2];
    #pragma unroll
    for (int ci = 0; ci < 4; ++ci)
      #pragma unroll
      for (int x2 = 0; x2 < 2; ++x2)
        bk[ci][x2] = *reinterpret_cast<const short8*>(kb + (size_t)(kv0 + ci * 16 + lr) * DH + x2 * 32 + lg * 8);
    f32x4 sc[2][4];
    #pragma unroll
    for (int mi = 0; mi < 2; ++mi)
      #pragma unroll
      for (int ci = 0; ci < 4; ++ci) {
        f32x4 s = (f32x4){0.f, 0.f, 0.f, 0.f};
        s = __builtin_amdgcn_mfma_f32_16x16x32_bf16(aq[mi][0], bk[ci][0], s, 0, 0, 0);
        s = __builtin_amdgcn_mfma_f32_16x16x32_bf16(aq[mi][1], bk[ci][1], s, 0, 0, 0);
        sc[mi][ci] = s;
      }
    #pragma unroll
    for (int mi = 0; mi < 2; ++mi)
      #pragma unroll
      for (int ci = 0; ci < 4; ++ci)
        #pragma unroll
        for (int r = 0; r < 4; ++r) {
          int qq = q0 + mi * 16 + lg * 4 + r;
          int kv = kv0 + ci * 16 + lr;
          float v = sc[mi][ci][r] * 0.125f;
          sc[mi][ci][r] = (kv <= qq) ? v : -1e30f;
        }
    // ---- online softmax (rows live in 16-lane groups)
    #pragma unroll
    for (int mi = 0; mi < 2; ++mi)
      #pragma unroll
      for (int r = 0; r < 4; ++r) {
        float mx = fmaxf(fmaxf(sc[mi][0][r], sc[mi][1][r]), fmaxf(sc[mi][2][r], sc[mi][3][r]));
        #pragma unroll
        for (int off = 1; off < 16; off <<= 1) mx = fmaxf(mx, __shfl_xor(mx, off));
        float mnew = fmaxf(mrow[mi][r], mx);
        float corr = __expf(mrow[mi][r] - mnew);
        mrow[mi][r] = mnew;
        float rs = 0.f;
        #pragma unroll
        for (int ci = 0; ci < 4; ++ci) {
          float p = __expf(sc[mi][ci][r] - mnew);
          rs += p;
          plds[w][mi * 16 + lg * 4 + r][ci * 16 + lr] = f2bf(p);
        }
        #pragma unroll
        for (int off = 1; off < 16; off <<= 1) rs += __shfl_xor(rs, off);
        lsum[mi][r] = lsum[mi][r] * corr + rs;
        #pragma unroll
        for (int ci = 0; ci < 4; ++ci) oacc[mi][ci][r] *= corr;
      }
    // ---- O += P V  (P from LDS, V^T from global)
    #pragma unroll
    for (int x2 = 0; x2 < 2; ++x2) {
      short8 ap[2], bv[4];
      #pragma unroll
      for (int mi = 0; mi < 2; ++mi)
        ap[mi] = *reinterpret_cast<const short8*>(&plds[w][mi * 16 + lr][x2 * 32 + lg * 8]);
      #pragma unroll
      for (int ci = 0; ci < 4; ++ci)
        bv[ci] = *reinterpret_cast<const short8*>(vb + (size_t)(ci * 16 + lr) * SQ + kv0 + x2 * 32 + lg * 8);
      #pragma unroll
      for (int mi = 0; mi < 2; ++mi)
        #pragma unroll
        for (int ci = 0; ci < 4; ++ci)
          oacc[mi][ci] = __builtin_amdgcn_mfma_f32_16x16x32_bf16(ap[mi], bv[ci], oacc[mi][ci], 0, 0, 0);
    }
  }
  // ---- epilogue: normalize, write [b][s][h*64+e]
  #pragma unroll
  for (int mi = 0; mi < 2; ++mi)
    #pragma unroll
    for (int ci = 0; ci < 4; ++ci)
      #pragma unroll
      for (int r = 0; r < 4; ++r) {
        int sl = q0 + mi * 16 + lg * 4 + r;
        int e  = ci * 16 + lr;
        out[((size_t)b * SQ + sl) * (NH * DH) + h * DH + e] = oacc[mi][ci][r] / lsum[mi][r];
      }
}

extern "C" void kernel_launch(void* const* d_in, const int* in_sizes, int n_in,
                              void* d_out, int out_size, void* d_ws, size_t ws_size,
                              hipStream_t stream) {
  const float* x  = (const float*)d_in[0];
  const float* Wq = (const float*)d_in[1];
  const float* Wk = (const float*)d_in[2];
  const float* Wv = (const float*)d_in[3];
  float* out = (float*)d_out;

  char* ws = (char*)d_ws;
  // byte offsets into workspace
  ushort* xb = (ushort*)(ws);                        // 8192*768 bf16   = 12,582,912 B
  ushort* wt = (ushort*)(ws + 12582912);             // 36*64*768 bf16  =  3,538,944 B
  ushort* q  = (ushort*)(ws + 16121856);             // 96*1024*64 bf16 = 12,582,912 B
  ushort* k  = (ushort*)(ws + 28704768);             // same
  ushort* vt = (ushort*)(ws + 41287680);             // same (transposed layout)

  k_convert_x<<<6144, 256, 0, stream>>>(x, xb);
  k_prep_w<<<36, 256, 0, stream>>>(Wq, Wk, Wv, wt);
  k_proj<<<dim3(64, 36), 256, 0, stream>>>(xb, wt, q, k, vt);
  k_attn<<<dim3(8, 96), 256, 0, stream>>>(q, k, vt, out);
}

// Round 2
// 280.198 us; speedup vs baseline: 1.4916x; 1.4916x over previous
//
#include <hip/hip_runtime.h>

typedef short short8 __attribute__((ext_vector_type(8)));
typedef float f32x4 __attribute__((ext_vector_type(4)));

#define SQ   1024
#define DIN  768
#define NH   12
#define DH   64

static __device__ __forceinline__ ushort f2bf(float f) {
  union { float f; unsigned u; } v; v.f = f;
  unsigned u = v.u;
  unsigned r = (u + 0x7FFFu + ((u >> 16) & 1u)) >> 16;
  return (ushort)r;
}

static __device__ __forceinline__ void gload_lds16(const ushort* g, ushort* l) {
  __builtin_amdgcn_global_load_lds(
      (const __attribute__((address_space(1))) unsigned*)(g),
      (__attribute__((address_space(3))) unsigned*)(l),
      16, 0, 0);
}

// ---------------------------------------------------------------- prep: x -> bf16
__global__ __launch_bounds__(256) void k_convert_x(const float* __restrict__ x,
                                                   ushort* __restrict__ xb) {
  int i = (blockIdx.x * 256 + threadIdx.x) * 4;
  float4 v = *reinterpret_cast<const float4*>(x + i);
  ushort4 o;
  o.x = f2bf(v.x); o.y = f2bf(v.y); o.z = f2bf(v.z); o.w = f2bf(v.w);
  *reinterpret_cast<ushort4*>(xb + i) = o;
}

// ------------------------------- prep: W[h][d][e] -> Wt[(m*12+h)*64+e][d] bf16 (B^T)
// grid (36, 12): one 64x64 tile each
__global__ __launch_bounds__(256) void k_prep_w(const float* __restrict__ Wq,
                                                const float* __restrict__ Wk,
                                                const float* __restrict__ Wv,
                                                ushort* __restrict__ wt) {
  __shared__ ushort tile[64][65];
  const int mh = blockIdx.x;            // m*12 + h
  const int m = mh / 12, h = mh % 12;
  const int d0 = blockIdx.y * 64;
  const float* W = (m == 0 ? Wq : (m == 1 ? Wk : Wv)) + h * DIN * DH;
  ushort* outp = wt + (size_t)mh * DH * DIN;
  #pragma unroll
  for (int p = 0; p < 16; ++p) {
    int idx = p * 256 + threadIdx.x;
    int d = idx >> 6, e = idx & 63;
    tile[d][e] = f2bf(W[(d0 + d) * DH + e]);
  }
  __syncthreads();
  #pragma unroll
  for (int p = 0; p < 16; ++p) {
    int idx = p * 256 + threadIdx.x;
    int e = idx >> 6, d = idx & 63;
    outp[e * DIN + d0 + d] = tile[d][e];
  }
}

// ------------------------------------------------- QKV projection as ONE GEMM
// C[8192 x 2304] = xb[8192 x 768] * wt^T (wt is [2304 x 768] row-major = B^T)
// m97 structure: 128x128 tile, BK=32, 4 waves (2x2) each 64x64, global_load_lds w=16,
// double-buffered LDS, slot^=(row&3) involution swizzle (pre-swizzled source + swizzled read).
__global__ __launch_bounds__(256) void k_proj(const ushort* __restrict__ xb,
                                              const ushort* __restrict__ wt,
                                              ushort* __restrict__ qo,
                                              ushort* __restrict__ ko,
                                              ushort* __restrict__ vto) {
  __shared__ __align__(16) ushort Ab[2][128][32];   // 8 KB per buffer
  __shared__ __align__(16) ushort Bb[2][128][32];

  const int brow = blockIdx.x * 128;     // M base (flat b*1024+s)
  const int bn   = blockIdx.y * 128;     // N base (mh*64+e)
  const int w    = threadIdx.x >> 6, lane = threadIdx.x & 63;
  const int lr   = lane & 15, lg = lane >> 4;
  const int wm   = w >> 1, wn = w & 1;   // 2x2 wave grid, each 64x64

  // --- staging addresses (thread t covers LDS bytes [t*16, t*16+16) of each half-tile)
  const int srow  = threadIdx.x >> 2;                 // 0..63
  const int sslot = (threadIdx.x & 3) ^ (srow & 3);   // involution swizzle on source
  const ushort* gA = xb + (size_t)(brow + srow) * DIN + sslot * 8;
  const ushort* gB = wt + (size_t)(bn   + srow) * DIN + sslot * 8;
  ushort* lA = &Ab[0][0][0] + threadIdx.x * 8;        // HW: wave-uniform base + lane*16B
  ushort* lB = &Bb[0][0][0] + threadIdx.x * 8;

  f32x4 acc[4][4];
  #pragma unroll
  for (int i = 0; i < 4; ++i)
    #pragma unroll
    for (int j = 0; j < 4; ++j) acc[i][j] = (f32x4){0.f, 0.f, 0.f, 0.f};

  const int aslot = (lg ^ (lr & 3)) * 8;              // swizzled read slot (elems)

  // prologue: stage tile 0 into buf 0
  gload_lds16(gA,            lA);
  gload_lds16(gA + 64 * DIN, lA + 2048);
  gload_lds16(gB,            lB);
  gload_lds16(gB + 64 * DIN, lB + 2048);
  __syncthreads();

  int cur = 0;
  #pragma unroll 1
  for (int t = 0; t < 24; ++t) {
    if (t + 1 < 24) {
      const int k0 = (t + 1) * 32;
      const int nb = (cur ^ 1) * 4096;
      gload_lds16(gA + k0,            lA + nb);
      gload_lds16(gA + k0 + 64 * DIN, lA + nb + 2048);
      gload_lds16(gB + k0,            lB + nb);
      gload_lds16(gB + k0 + 64 * DIN, lB + nb + 2048);
    }
    short8 a[4], b[4];
    #pragma unroll
    for (int mi = 0; mi < 4; ++mi)
      a[mi] = *reinterpret_cast<const short8*>(&Ab[cur][wm * 64 + mi * 16 + lr][aslot]);
    #pragma unroll
    for (int ci = 0; ci < 4; ++ci)
      b[ci] = *reinterpret_cast<const short8*>(&Bb[cur][wn * 64 + ci * 16 + lr][aslot]);
    #pragma unroll
    for (int mi = 0; mi < 4; ++mi)
      #pragma unroll
      for (int ci = 0; ci < 4; ++ci)
        acc[mi][ci] = __builtin_amdgcn_mfma_f32_16x16x32_bf16(a[mi], b[ci], acc[mi][ci], 0, 0, 0);
    __syncthreads();
    cur ^= 1;
  }

  // --- epilogue: scatter to Q [bh][s][e], K [bh][s][e], V^T [bh][e][s]
  const int mh = (bn + wn * 64) >> 6;   // uniform per wave
  const int m = mh / 12, h = mh % 12;
  #pragma unroll
  for (int mi = 0; mi < 4; ++mi)
    #pragma unroll
    for (int ci = 0; ci < 4; ++ci)
      #pragma unroll
      for (int r = 0; r < 4; ++r) {
        int rg = brow + wm * 64 + mi * 16 + lg * 4 + r;
        int b_ = rg >> 10, sl = rg & 1023;
        int bh = b_ * 12 + h;
        int e  = ci * 16 + lr;
        ushort val = f2bf(acc[mi][ci][r]);
        if (m == 2) {
          vto[((size_t)bh * DH + e) * SQ + sl] = val;
        } else {
          ushort* dst = (m == 0) ? qo : ko;
          dst[((size_t)bh * SQ + sl) * DH + e] = val;
        }
      }
}

// ------------------------------------------------- fused causal flash attention
// grid: (8 q-tiles of 128, 96 = b*12+h); block 256; 4 independent waves (32 q-rows each)
__global__ __launch_bounds__(256) void k_attn(const ushort* __restrict__ qi,
                                              const ushort* __restrict__ ki,
                                              const ushort* __restrict__ vti,
                                              float* __restrict__ out) {
  __shared__ __align__(16) ushort plds[4][32][72];   // per-wave P tile, padded (72) for b128 reads
  const int bh = blockIdx.y;
  const int b = bh / 12, h = bh % 12;
  const int w = threadIdx.x >> 6, lane = threadIdx.x & 63;
  const int lr = lane & 15, lg = lane >> 4;
  const int q0 = blockIdx.x * 128 + w * 32;          // s_local base for this wave
  const ushort* qb = qi  + (size_t)bh * SQ * DH;
  const ushort* kb = ki  + (size_t)bh * SQ * DH;
  const ushort* vb = vti + (size_t)bh * DH * SQ;

  short8 aq[2][2];
  #pragma unroll
  for (int mi = 0; mi < 2; ++mi)
    #pragma unroll
    for (int x2 = 0; x2 < 2; ++x2)
      aq[mi][x2] = *reinterpret_cast<const short8*>(qb + (size_t)(q0 + mi * 16 + lr) * DH + x2 * 32 + lg * 8);

  f32x4 oacc[2][4];
  float mrow[2][4], lsum[2][4];
  #pragma unroll
  for (int mi = 0; mi < 2; ++mi) {
    #pragma unroll
    for (int ci = 0; ci < 4; ++ci) oacc[mi][ci] = (f32x4){0.f, 0.f, 0.f, 0.f};
    #pragma unroll
    for (int r = 0; r < 4; ++r) { mrow[mi][r] = -1e30f; lsum[mi][r] = 0.f; }
  }

  const int nt = (q0 + 31) / 64 + 1;
  for (int t = 0; t < nt; ++t) {
    const int kv0 = t * 64;
    // ---- S = Q K^T * scale, causal mask
    short8 bk[4][2];
    #pragma unroll
    for (int ci = 0; ci < 4; ++ci)
      #pragma unroll
      for (int x2 = 0; x2 < 2; ++x2)
        bk[ci][x2] = *reinterpret_cast<const short8*>(kb + (size_t)(kv0 + ci * 16 + lr) * DH + x2 * 32 + lg * 8);
    f32x4 sc[2][4];
    #pragma unroll
    for (int mi = 0; mi < 2; ++mi)
      #pragma unroll
      for (int ci = 0; ci < 4; ++ci) {
        f32x4 s = (f32x4){0.f, 0.f, 0.f, 0.f};
        s = __builtin_amdgcn_mfma_f32_16x16x32_bf16(aq[mi][0], bk[ci][0], s, 0, 0, 0);
        s = __builtin_amdgcn_mfma_f32_16x16x32_bf16(aq[mi][1], bk[ci][1], s, 0, 0, 0);
        sc[mi][ci] = s;
      }
    #pragma unroll
    for (int mi = 0; mi < 2; ++mi)
      #pragma unroll
      for (int ci = 0; ci < 4; ++ci)
        #pragma unroll
        for (int r = 0; r < 4; ++r) {
          int qq = q0 + mi * 16 + lg * 4 + r;
          int kv = kv0 + ci * 16 + lr;
          float v = sc[mi][ci][r] * 0.125f;
          sc[mi][ci][r] = (kv <= qq) ? v : -1e30f;
        }
    // ---- online softmax (rows live in 16-lane groups)
    #pragma unroll
    for (int mi = 0; mi < 2; ++mi)
      #pragma unroll
      for (int r = 0; r < 4; ++r) {
        float mx = fmaxf(fmaxf(sc[mi][0][r], sc[mi][1][r]), fmaxf(sc[mi][2][r], sc[mi][3][r]));
        #pragma unroll
        for (int off = 1; off < 16; off <<= 1) mx = fmaxf(mx, __shfl_xor(mx, off));
        float mnew = fmaxf(mrow[mi][r], mx);
        float corr = __expf(mrow[mi][r] - mnew);
        mrow[mi][r] = mnew;
        float rs = 0.f;
        #pragma unroll
        for (int ci = 0; ci < 4; ++ci) {
          float p = __expf(sc[mi][ci][r] - mnew);
          rs += p;
          plds[w][mi * 16 + lg * 4 + r][ci * 16 + lr] = f2bf(p);
        }
        #pragma unroll
        for (int off = 1; off < 16; off <<= 1) rs += __shfl_xor(rs, off);
        lsum[mi][r] = lsum[mi][r] * corr + rs;
        #pragma unroll
        for (int ci = 0; ci < 4; ++ci) oacc[mi][ci][r] *= corr;
      }
    // ---- O += P V  (P from LDS, V^T from global)
    #pragma unroll
    for (int x2 = 0; x2 < 2; ++x2) {
      short8 ap[2], bv[4];
      #pragma unroll
      for (int mi = 0; mi < 2; ++mi)
        ap[mi] = *reinterpret_cast<const short8*>(&plds[w][mi * 16 + lr][x2 * 32 + lg * 8]);
      #pragma unroll
      for (int ci = 0; ci < 4; ++ci)
        bv[ci] = *reinterpret_cast<const short8*>(vb + (size_t)(ci * 16 + lr) * SQ + kv0 + x2 * 32 + lg * 8);
      #pragma unroll
      for (int mi = 0; mi < 2; ++mi)
        #pragma unroll
        for (int ci = 0; ci < 4; ++ci)
          oacc[mi][ci] = __builtin_amdgcn_mfma_f32_16x16x32_bf16(ap[mi], bv[ci], oacc[mi][ci], 0, 0, 0);
    }
  }
  // ---- epilogue: normalize, write [b][s][h*64+e]
  #pragma unroll
  for (int mi = 0; mi < 2; ++mi)
    #pragma unroll
    for (int ci = 0; ci < 4; ++ci)
      #pragma unroll
      for (int r = 0; r < 4; ++r) {
        int sl = q0 + mi * 16 + lg * 4 + r;
        int e  = ci * 16 + lr;
        out[((size_t)b * SQ + sl) * (NH * DH) + h * DH + e] = oacc[mi][ci][r] / lsum[mi][r];
      }
}

extern "C" void kernel_launch(void* const* d_in, const int* in_sizes, int n_in,
                              void* d_out, int out_size, void* d_ws, size_t ws_size,
                              hipStream_t stream) {
  const float* x  = (const float*)d_in[0];
  const float* Wq = (const float*)d_in[1];
  const float* Wk = (const float*)d_in[2];
  const float* Wv = (const float*)d_in[3];
  float* out = (float*)d_out;

  char* ws = (char*)d_ws;
  ushort* xb = (ushort*)(ws);                        // 8192*768 bf16   = 12,582,912 B
  ushort* wt = (ushort*)(ws + 12582912);             // 2304*768 bf16   =  3,538,944 B
  ushort* q  = (ushort*)(ws + 16121856);             // 96*1024*64 bf16 = 12,582,912 B
  ushort* k  = (ushort*)(ws + 28704768);             // same
  ushort* vt = (ushort*)(ws + 41287680);             // same (transposed layout)

  k_convert_x<<<6144, 256, 0, stream>>>(x, xb);
  k_prep_w<<<dim3(36, 12), 256, 0, stream>>>(Wq, Wk, Wv, wt);
  k_proj<<<dim3(64, 18), 256, 0, stream>>>(xb, wt, q, k, vt);
  k_attn<<<dim3(8, 96), 256, 0, stream>>>(q, k, vt, out);
}

// Round 3
// 266.298 us; speedup vs baseline: 1.5694x; 1.0522x over previous
//
#include <hip/hip_runtime.h>

typedef short short8 __attribute__((ext_vector_type(8)));
typedef float f32x4 __attribute__((ext_vector_type(4)));

#define SQ   1024
#define DIN  768
#define NH   12
#define DH   64
#define SCL2 0.1803368801111243f   /* 0.125 * log2(e) */

static __device__ __forceinline__ ushort f2bf(float f) {
  union { float f; unsigned u; } v; v.f = f;
  unsigned u = v.u;
  unsigned r = (u + 0x7FFFu + ((u >> 16) & 1u)) >> 16;
  return (ushort)r;
}

static __device__ __forceinline__ void gload_lds16(const ushort* g, ushort* l) {
  __builtin_amdgcn_global_load_lds(
      (const __attribute__((address_space(1))) unsigned*)(g),
      (__attribute__((address_space(3))) unsigned*)(l),
      16, 0, 0);
}

// ---------------------------------------------------------------- prep: x -> bf16
__global__ __launch_bounds__(256) void k_convert_x(const float* __restrict__ x,
                                                   ushort* __restrict__ xb) {
  int i = (blockIdx.x * 256 + threadIdx.x) * 4;
  float4 v = *reinterpret_cast<const float4*>(x + i);
  ushort4 o;
  o.x = f2bf(v.x); o.y = f2bf(v.y); o.z = f2bf(v.z); o.w = f2bf(v.w);
  *reinterpret_cast<ushort4*>(xb + i) = o;
}

// ------------------------------- prep: W[h][d][e] -> Wt[(m*12+h)*64+e][d] bf16 (B^T)
__global__ __launch_bounds__(256) void k_prep_w(const float* __restrict__ Wq,
                                                const float* __restrict__ Wk,
                                                const float* __restrict__ Wv,
                                                ushort* __restrict__ wt) {
  __shared__ ushort tile[64][65];
  const int mh = blockIdx.x;            // m*12 + h
  const int m = mh / 12, h = mh % 12;
  const int d0 = blockIdx.y * 64;
  const float* W = (m == 0 ? Wq : (m == 1 ? Wk : Wv)) + h * DIN * DH;
  ushort* outp = wt + (size_t)mh * DH * DIN;
  #pragma unroll
  for (int p = 0; p < 16; ++p) {
    int idx = p * 256 + threadIdx.x;
    int d = idx >> 6, e = idx & 63;
    tile[d][e] = f2bf(W[(d0 + d) * DH + e]);
  }
  __syncthreads();
  #pragma unroll
  for (int p = 0; p < 16; ++p) {
    int idx = p * 256 + threadIdx.x;
    int e = idx >> 6, d = idx & 63;
    outp[e * DIN + d0 + d] = tile[d][e];
  }
}

// ------------------------------------------------- QKV projection as ONE GEMM
__global__ __launch_bounds__(256) void k_proj(const ushort* __restrict__ xb,
                                              const ushort* __restrict__ wt,
                                              ushort* __restrict__ qo,
                                              ushort* __restrict__ ko,
                                              ushort* __restrict__ vto) {
  __shared__ __align__(16) ushort Ab[2][128][32];
  __shared__ __align__(16) ushort Bb[2][128][32];

  const int brow = blockIdx.x * 128;
  const int bn   = blockIdx.y * 128;
  const int w    = threadIdx.x >> 6, lane = threadIdx.x & 63;
  const int lr   = lane & 15, lg = lane >> 4;
  const int wm   = w >> 1, wn = w & 1;

  const int srow  = threadIdx.x >> 2;
  const int sslot = (threadIdx.x & 3) ^ (srow & 3);
  const ushort* gA = xb + (size_t)(brow + srow) * DIN + sslot * 8;
  const ushort* gB = wt + (size_t)(bn   + srow) * DIN + sslot * 8;
  ushort* lA = &Ab[0][0][0] + threadIdx.x * 8;
  ushort* lB = &Bb[0][0][0] + threadIdx.x * 8;

  f32x4 acc[4][4];
  #pragma unroll
  for (int i = 0; i < 4; ++i)
    #pragma unroll
    for (int j = 0; j < 4; ++j) acc[i][j] = (f32x4){0.f, 0.f, 0.f, 0.f};

  const int aslot = (lg ^ (lr & 3)) * 8;

  gload_lds16(gA,            lA);
  gload_lds16(gA + 64 * DIN, lA + 2048);
  gload_lds16(gB,            lB);
  gload_lds16(gB + 64 * DIN, lB + 2048);
  __syncthreads();

  int cur = 0;
  #pragma unroll 1
  for (int t = 0; t < 24; ++t) {
    if (t + 1 < 24) {
      const int k0 = (t + 1) * 32;
      const int nb = (cur ^ 1) * 4096;
      gload_lds16(gA + k0,            lA + nb);
      gload_lds16(gA + k0 + 64 * DIN, lA + nb + 2048);
      gload_lds16(gB + k0,            lB + nb);
      gload_lds16(gB + k0 + 64 * DIN, lB + nb + 2048);
    }
    short8 a[4], b[4];
    #pragma unroll
    for (int mi = 0; mi < 4; ++mi)
      a[mi] = *reinterpret_cast<const short8*>(&Ab[cur][wm * 64 + mi * 16 + lr][aslot]);
    #pragma unroll
    for (int ci = 0; ci < 4; ++ci)
      b[ci] = *reinterpret_cast<const short8*>(&Bb[cur][wn * 64 + ci * 16 + lr][aslot]);
    #pragma unroll
    for (int mi = 0; mi < 4; ++mi)
      #pragma unroll
      for (int ci = 0; ci < 4; ++ci)
        acc[mi][ci] = __builtin_amdgcn_mfma_f32_16x16x32_bf16(a[mi], b[ci], acc[mi][ci], 0, 0, 0);
    __syncthreads();
    cur ^= 1;
  }

  const int mh = (bn + wn * 64) >> 6;
  const int m = mh / 12, h = mh % 12;
  #pragma unroll
  for (int mi = 0; mi < 4; ++mi)
    #pragma unroll
    for (int ci = 0; ci < 4; ++ci)
      #pragma unroll
      for (int r = 0; r < 4; ++r) {
        int rg = brow + wm * 64 + mi * 16 + lg * 4 + r;
        int b_ = rg >> 10, sl = rg & 1023;
        int bh = b_ * 12 + h;
        int e  = ci * 16 + lr;
        ushort val = f2bf(acc[mi][ci][r]);
        if (m == 2) {
          vto[((size_t)bh * DH + e) * SQ + sl] = val;
        } else {
          ushort* dst = (m == 0) ? qo : ko;
          dst[((size_t)bh * SQ + sl) * DH + e] = val;
        }
      }
}

// ------------------------------------------------- fused causal flash attention
// grid: (8 q-tiles HEAVY-FIRST, 96 = b*12+h); block 256 = 4 waves x 32 q-rows.
// K/V tiles double-buffered in LDS via global_load_lds (block-level, T3 2-phase),
// involution swizzle slot^=(row&7) (pre-swizzled source + swizzled ds_read).
__global__ __launch_bounds__(256) void k_attn(const ushort* __restrict__ qi,
                                              const ushort* __restrict__ ki,
                                              const ushort* __restrict__ vti,
                                              float* __restrict__ out) {
  __shared__ __align__(16) ushort Kb[2][64][64];
  __shared__ __align__(16) ushort Vb[2][64][64];
  __shared__ __align__(16) ushort plds[4][32][72];

  const int bh = blockIdx.y;
  const int b = bh / 12, h = bh % 12;
  const int w = threadIdx.x >> 6, lane = threadIdx.x & 63;
  const int lr = lane & 15, lg = lane >> 4;
  const int qt = 7 - blockIdx.x;                 // heavy blocks first
  const int q0 = qt * 128 + w * 32;
  const int nt = (q0 >> 6) + 1;                  // this wave's tile count
  const int ntmax = 2 * qt + 2;                  // block's tile count
  const ushort* qb = qi  + (size_t)bh * SQ * DH;
  const ushort* kb = ki  + (size_t)bh * SQ * DH;
  const ushort* vb = vti + (size_t)bh * DH * SQ;

  // staging ids: thread covers (row=tid>>3, 16B slot=tid&7), swizzled source slot
  const int srow = threadIdx.x >> 3;
  const int ksw  = ((threadIdx.x & 7) ^ (srow & 7)) * 8;

  short8 aq[2][2];
  #pragma unroll
  for (int mi = 0; mi < 2; ++mi)
    #pragma unroll
    for (int x2 = 0; x2 < 2; ++x2)
      aq[mi][x2] = *reinterpret_cast<const short8*>(qb + (size_t)(q0 + mi * 16 + lr) * DH + x2 * 32 + lg * 8);

  f32x4 oacc[2][4];
  float mrow[2][4], lsum[2][4];
  #pragma unroll
  for (int mi = 0; mi < 2; ++mi) {
    #pragma unroll
    for (int ci = 0; ci < 4; ++ci) oacc[mi][ci] = (f32x4){0.f, 0.f, 0.f, 0.f};
    #pragma unroll
    for (int r = 0; r < 4; ++r) { mrow[mi][r] = -1e30f; lsum[mi][r] = 0.f; }
  }

#define STAGE(bufi, tt) do {                                                        \
    const int kv0_ = (tt) * 64;                                                     \
    gload_lds16(kb + (size_t)(kv0_ + srow)      * DH + ksw, &Kb[bufi][0][0]  + threadIdx.x * 8); \
    gload_lds16(kb + (size_t)(kv0_ + srow + 32) * DH + ksw, &Kb[bufi][32][0] + threadIdx.x * 8); \
    gload_lds16(vb + (size_t)srow        * SQ + kv0_ + ksw, &Vb[bufi][0][0]  + threadIdx.x * 8); \
    gload_lds16(vb + (size_t)(srow + 32) * SQ + kv0_ + ksw, &Vb[bufi][32][0] + threadIdx.x * 8); \
  } while (0)

  STAGE(0, 0);
  __syncthreads();

  int cur = 0;
  #pragma unroll 1
  for (int t = 0; t < ntmax; ++t) {
    if (t + 1 < ntmax) STAGE(cur ^ 1, t + 1);

    if (t < nt) {
      const int kv0 = t * 64;
      // ---- S = Q K^T (raw units; scale folded into exp2 constant)
      short8 bk[4][2];
      #pragma unroll
      for (int ci = 0; ci < 4; ++ci) {
        const int row = ci * 16 + lr;
        #pragma unroll
        for (int x2 = 0; x2 < 2; ++x2)
          bk[ci][x2] = *reinterpret_cast<const short8*>(&Kb[cur][row][(((x2 * 4 + lg) ^ (row & 7)) * 8)]);
      }
      f32x4 sc[2][4];
      #pragma unroll
      for (int mi = 0; mi < 2; ++mi)
        #pragma unroll
        for (int ci = 0; ci < 4; ++ci) {
          f32x4 s = (f32x4){0.f, 0.f, 0.f, 0.f};
          s = __builtin_amdgcn_mfma_f32_16x16x32_bf16(aq[mi][0], bk[ci][0], s, 0, 0, 0);
          s = __builtin_amdgcn_mfma_f32_16x16x32_bf16(aq[mi][1], bk[ci][1], s, 0, 0, 0);
          sc[mi][ci] = s;
        }
      // ---- causal mask: only the diagonal tile
      if (t == nt - 1) {
        #pragma unroll
        for (int mi = 0; mi < 2; ++mi)
          #pragma unroll
          for (int ci = 0; ci < 4; ++ci)
            #pragma unroll
            for (int r = 0; r < 4; ++r) {
              int qq = q0 + mi * 16 + lg * 4 + r;
              int kv = kv0 + ci * 16 + lr;
              if (kv > qq) sc[mi][ci][r] = -1e30f;
            }
      }
      // ---- online softmax (rows in 16-lane groups), defer-rescale
      float mnew[2][4];
      bool ch = false;
      #pragma unroll
      for (int mi = 0; mi < 2; ++mi)
        #pragma unroll
        for (int r = 0; r < 4; ++r) {
          float mx = fmaxf(fmaxf(sc[mi][0][r], sc[mi][1][r]), fmaxf(sc[mi][2][r], sc[mi][3][r]));
          #pragma unroll
          for (int off = 1; off < 16; off <<= 1) mx = fmaxf(mx, __shfl_xor(mx, off));
          mnew[mi][r] = fmaxf(mrow[mi][r], mx);
          ch = ch || (mnew[mi][r] > mrow[mi][r]);
        }
      if (__any(ch)) {
        #pragma unroll
        for (int mi = 0; mi < 2; ++mi)
          #pragma unroll
          for (int r = 0; r < 4; ++r) {
            float corr = exp2f((mrow[mi][r] - mnew[mi][r]) * SCL2);
            lsum[mi][r] *= corr;
            mrow[mi][r] = mnew[mi][r];
            #pragma unroll
            for (int ci = 0; ci < 4; ++ci) oacc[mi][ci][r] *= corr;
          }
      }
      #pragma unroll
      for (int mi = 0; mi < 2; ++mi)
        #pragma unroll
        for (int r = 0; r < 4; ++r) {
          float rs = 0.f;
          #pragma unroll
          for (int ci = 0; ci < 4; ++ci) {
            float p = exp2f((sc[mi][ci][r] - mrow[mi][r]) * SCL2);
            rs += p;
            plds[w][mi * 16 + lg * 4 + r][ci * 16 + lr] = f2bf(p);
          }
          #pragma unroll
          for (int off = 1; off < 16; off <<= 1) rs += __shfl_xor(rs, off);
          lsum[mi][r] += rs;
        }
      // ---- O += P V  (P from LDS, V^T tile from LDS, swizzled)
      #pragma unroll
      for (int x2 = 0; x2 < 2; ++x2) {
        short8 ap[2], bv[4];
        #pragma unroll
        for (int mi = 0; mi < 2; ++mi)
          ap[mi] = *reinterpret_cast<const short8*>(&plds[w][mi * 16 + lr][x2 * 32 + lg * 8]);
        #pragma unroll
        for (int ci = 0; ci < 4; ++ci) {
          const int row = ci * 16 + lr;
          bv[ci] = *reinterpret_cast<const short8*>(&Vb[cur][row][(((x2 * 4 + lg) ^ (row & 7)) * 8)]);
        }
        #pragma unroll
        for (int mi = 0; mi < 2; ++mi)
          #pragma unroll
          for (int ci = 0; ci < 4; ++ci)
            oacc[mi][ci] = __builtin_amdgcn_mfma_f32_16x16x32_bf16(ap[mi], bv[ci], oacc[mi][ci], 0, 0, 0);
      }
    }

    __syncthreads();
    cur ^= 1;
  }
#undef STAGE

  // ---- epilogue: normalize, write [b][s][h*64+e]
  #pragma unroll
  for (int mi = 0; mi < 2; ++mi)
    #pragma unroll
    for (int ci = 0; ci < 4; ++ci)
      #pragma unroll
      for (int r = 0; r < 4; ++r) {
        int sl = q0 + mi * 16 + lg * 4 + r;
        int e  = ci * 16 + lr;
        out[((size_t)b * SQ + sl) * (NH * DH) + h * DH + e] = oacc[mi][ci][r] / lsum[mi][r];
      }
}

extern "C" void kernel_launch(void* const* d_in, const int* in_sizes, int n_in,
                              void* d_out, int out_size, void* d_ws, size_t ws_size,
                              hipStream_t stream) {
  const float* x  = (const float*)d_in[0];
  const float* Wq = (const float*)d_in[1];
  const float* Wk = (const float*)d_in[2];
  const float* Wv = (const float*)d_in[3];
  float* out = (float*)d_out;

  char* ws = (char*)d_ws;
  ushort* xb = (ushort*)(ws);
  ushort* wt = (ushort*)(ws + 12582912);
  ushort* q  = (ushort*)(ws + 16121856);
  ushort* k  = (ushort*)(ws + 28704768);
  ushort* vt = (ushort*)(ws + 41287680);

  k_convert_x<<<6144, 256, 0, stream>>>(x, xb);
  k_prep_w<<<dim3(36, 12), 256, 0, stream>>>(Wq, Wk, Wv, wt);
  k_proj<<<dim3(64, 18), 256, 0, stream>>>(xb, wt, q, k, vt);
  k_attn<<<dim3(8, 96), 256, 0, stream>>>(q, k, vt, out);
}

// Round 6
// 198.007 us; speedup vs baseline: 2.1107x; 1.3449x over previous
//
#include <hip/hip_runtime.h>

typedef short short8 __attribute__((ext_vector_type(8)));
typedef float f32x4 __attribute__((ext_vector_type(4)));
typedef float f32x16 __attribute__((ext_vector_type(16)));

#define SQ   1024
#define DIN  768
#define NH   12
#define DH   64
#define SCL2 0.1803368801111243f   /* 0.125 * log2(e) */

static __device__ __forceinline__ ushort f2bf(float f) {
  union { float f; unsigned u; } v; v.f = f;
  unsigned u = v.u;
  unsigned r = (u + 0x7FFFu + ((u >> 16) & 1u)) >> 16;
  return (ushort)r;
}
static __device__ __forceinline__ unsigned pk2(float a, float b) {
  return (unsigned)f2bf(a) | ((unsigned)f2bf(b) << 16);
}

static __device__ __forceinline__ void gload_lds16(const ushort* g, ushort* l) {
  __builtin_amdgcn_global_load_lds(
      (const __attribute__((address_space(1))) unsigned*)(g),
      (__attribute__((address_space(3))) unsigned*)(l),
      16, 0, 0);
}

// ---------------------------------------------------------------- prep: x -> bf16
__global__ __launch_bounds__(256) void k_convert_x(const float* __restrict__ x,
                                                   ushort* __restrict__ xb) {
  int i = (blockIdx.x * 256 + threadIdx.x) * 4;
  float4 v = *reinterpret_cast<const float4*>(x + i);
  ushort4 o;
  o.x = f2bf(v.x); o.y = f2bf(v.y); o.z = f2bf(v.z); o.w = f2bf(v.w);
  *reinterpret_cast<ushort4*>(xb + i) = o;
}

// ------------------------------- prep: W[h][d][e] -> Wt[(m*12+h)*64+e][d] bf16 (B^T)
__global__ __launch_bounds__(256) void k_prep_w(const float* __restrict__ Wq,
                                                const float* __restrict__ Wk,
                                                const float* __restrict__ Wv,
                                                ushort* __restrict__ wt) {
  __shared__ ushort tile[64][65];
  const int mh = blockIdx.x;            // m*12 + h
  const int m = mh / 12, h = mh % 12;
  const int d0 = blockIdx.y * 64;
  const float* W = (m == 0 ? Wq : (m == 1 ? Wk : Wv)) + h * DIN * DH;
  ushort* outp = wt + (size_t)mh * DH * DIN;
  #pragma unroll
  for (int p = 0; p < 16; ++p) {
    int idx = p * 256 + threadIdx.x;
    int d = idx >> 6, e = idx & 63;
    tile[d][e] = f2bf(W[(d0 + d) * DH + e]);
  }
  __syncthreads();
  #pragma unroll
  for (int p = 0; p < 16; ++p) {
    int idx = p * 256 + threadIdx.x;
    int e = idx >> 6, d = idx & 63;
    outp[e * DIN + d0 + d] = tile[d][e];
  }
}

// ------------------------------------------------- QKV projection as ONE GEMM
__global__ __launch_bounds__(256) void k_proj(const ushort* __restrict__ xb,
                                              const ushort* __restrict__ wt,
                                              ushort* __restrict__ qo,
                                              ushort* __restrict__ ko,
                                              ushort* __restrict__ vto) {
  __shared__ __align__(16) ushort Ab[2][128][32];
  __shared__ __align__(16) ushort Bb[2][128][32];

  const int brow = blockIdx.x * 128;
  const int bn   = blockIdx.y * 128;
  const int w    = threadIdx.x >> 6, lane = threadIdx.x & 63;
  const int lr   = lane & 15, lg = lane >> 4;
  const int wm   = w >> 1, wn = w & 1;

  const int srow  = threadIdx.x >> 2;
  const int sslot = (threadIdx.x & 3) ^ (srow & 3);
  const ushort* gA = xb + (size_t)(brow + srow) * DIN + sslot * 8;
  const ushort* gB = wt + (size_t)(bn   + srow) * DIN + sslot * 8;
  ushort* lA = &Ab[0][0][0] + threadIdx.x * 8;
  ushort* lB = &Bb[0][0][0] + threadIdx.x * 8;

  f32x4 acc[4][4];
  #pragma unroll
  for (int i = 0; i < 4; ++i)
    #pragma unroll
    for (int j = 0; j < 4; ++j) acc[i][j] = (f32x4){0.f, 0.f, 0.f, 0.f};

  const int aslot = (lg ^ (lr & 3)) * 8;

  gload_lds16(gA,            lA);
  gload_lds16(gA + 64 * DIN, lA + 2048);
  gload_lds16(gB,            lB);
  gload_lds16(gB + 64 * DIN, lB + 2048);
  __syncthreads();

  int cur = 0;
  #pragma unroll 1
  for (int t = 0; t < 24; ++t) {
    if (t + 1 < 24) {
      const int k0 = (t + 1) * 32;
      const int nb = (cur ^ 1) * 4096;
      gload_lds16(gA + k0,            lA + nb);
      gload_lds16(gA + k0 + 64 * DIN, lA + nb + 2048);
      gload_lds16(gB + k0,            lB + nb);
      gload_lds16(gB + k0 + 64 * DIN, lB + nb + 2048);
    }
    short8 a[4], b[4];
    #pragma unroll
    for (int mi = 0; mi < 4; ++mi)
      a[mi] = *reinterpret_cast<const short8*>(&Ab[cur][wm * 64 + mi * 16 + lr][aslot]);
    #pragma unroll
    for (int ci = 0; ci < 4; ++ci)
      b[ci] = *reinterpret_cast<const short8*>(&Bb[cur][wn * 64 + ci * 16 + lr][aslot]);
    #pragma unroll
    for (int mi = 0; mi < 4; ++mi)
      #pragma unroll
      for (int ci = 0; ci < 4; ++ci)
        acc[mi][ci] = __builtin_amdgcn_mfma_f32_16x16x32_bf16(a[mi], b[ci], acc[mi][ci], 0, 0, 0);
    __syncthreads();
    cur ^= 1;
  }

  const int mh = (bn + wn * 64) >> 6;
  const int m = mh / 12, h = mh % 12;
  #pragma unroll
  for (int mi = 0; mi < 4; ++mi)
    #pragma unroll
    for (int ci = 0; ci < 4; ++ci)
      #pragma unroll
      for (int r = 0; r < 4; ++r) {
        int rg = brow + wm * 64 + mi * 16 + lg * 4 + r;
        int b_ = rg >> 10, sl = rg & 1023;
        int bh = b_ * 12 + h;
        int e  = ci * 16 + lr;
        ushort val = f2bf(acc[mi][ci][r]);
        if (m == 2) {
          vto[((size_t)bh * DH + e) * SQ + sl] = val;
        } else {
          ushort* dst = (m == 0) ? qo : ko;
          dst[((size_t)bh * SQ + sl) * DH + e] = val;
        }
      }
}

// ------------------------------------------------- fused causal flash attention
// m214-style: swapped QK^T (S^T = mfma32(K, Q)), in-register softmax + in-register
// P->PV via pack + shfl_xor(32)+select. 4 waves x 32 q-rows; KVBLK=64; K/V^T in LDS
// (double-buffered, global_load_lds w=16, both-sides XOR swizzle). No P LDS.
// grid: 768 flat, nonlinear (qt,bh) remap to break per-CU same-qt alignment.
__global__ __launch_bounds__(256, 3) void k_attn(const ushort* __restrict__ qi,
                                                 const ushort* __restrict__ ki,
                                                 const ushort* __restrict__ vti,
                                                 float* __restrict__ out) {
  __shared__ __align__(16) ushort Kb[2][64 * 64];
  __shared__ __align__(16) ushort Vb[2][64 * 64];

  const int f = blockIdx.x;
  const int g = f >> 8, r_ = f & 255;
  const int qt = ((r_ & 7) + g * 3) & 7;        // bijective, breaks 256-stride alignment
  const int bh = g * 32 + (r_ >> 3);
  const int b = bh / 12, h = bh % 12;
  const int w = threadIdx.x >> 6, lane = threadIdx.x & 63;
  const int ql = lane & 31, hi = lane >> 5;
  const int q0 = qt * 128 + w * 32;
  const int nt = (q0 >> 6) + 1;                 // this wave's kv-tile count
  const int ntmax = 2 * qt + 2;                 // block's kv-tile count
  const ushort* qb = qi  + (size_t)bh * SQ * DH;
  const ushort* kb = ki  + (size_t)bh * SQ * DH;
  const ushort* vb = vti + (size_t)bh * DH * SQ;

  // Q as B-fragments: lane holds Q[q0+ql][d = m*16 + hi*8 + j]
  short8 qf[4];
  #pragma unroll
  for (int m = 0; m < 4; ++m)
    qf[m] = *reinterpret_cast<const short8*>(qb + (size_t)(q0 + ql) * DH + m * 16 + hi * 8);

  f32x16 o0, o1;                                 // O[e-half][reg->q]; col e = eh*32+ql
  #pragma unroll
  for (int r = 0; r < 16; ++r) { o0[r] = 0.f; o1[r] = 0.f; }
  float m_run = -1e30f, l_run = 0.f;

#define STAGE(bufi, tt) do {                                                                   \
    const int kv0_ = (tt) * 64;                                                                \
    const int t0 = threadIdx.x, t1 = threadIdx.x + 256;                                        \
    gload_lds16(kb + (size_t)(kv0_ + (t0 >> 3)) * DH + (((t0 & 7) ^ ((t0 >> 3) & 7)) * 8),     \
                &Kb[bufi][0] + t0 * 8);                                                        \
    gload_lds16(kb + (size_t)(kv0_ + (t1 >> 3)) * DH + (((t1 & 7) ^ ((t1 >> 3) & 7)) * 8),     \
                &Kb[bufi][0] + t1 * 8);                                                        \
    gload_lds16(vb + (size_t)(t0 >> 3) * SQ + kv0_ + (((t0 & 7) ^ ((t0 >> 3) & 7)) * 8),       \
                &Vb[bufi][0] + t0 * 8);                                                        \
    gload_lds16(vb + (size_t)(t1 >> 3) * SQ + kv0_ + (((t1 & 7) ^ ((t1 >> 3) & 7)) * 8),       \
                &Vb[bufi][0] + t1 * 8);                                                        \
  } while (0)

  STAGE(0, 0);
  __syncthreads();

  int cur = 0;
  #pragma unroll 1
  for (int t = 0; t < ntmax; ++t) {
    if (t + 1 < ntmax) STAGE(cur ^ 1, t + 1);

    if (t < nt) {
      const int kv0 = t * 64;
      const ushort* Kc = &Kb[cur][0];
      const ushort* Vc = &Vb[cur][0];

      // ---- S^T = K Q^T : two 32x32 subtiles (kv 0-31, 32-63), k=4 chunks of 16
      f32x16 s0, s1;
      #pragma unroll
      for (int r = 0; r < 16; ++r) { s0[r] = 0.f; s1[r] = 0.f; }
      #pragma unroll
      for (int m = 0; m < 4; ++m) {
        short8 kf = *reinterpret_cast<const short8*>(Kc + ql * 64 + ((2 * m + hi) ^ (ql & 7)) * 8);
        s0 = __builtin_amdgcn_mfma_f32_32x32x16_bf16(kf, qf[m], s0, 0, 0, 0);
      }
      #pragma unroll
      for (int m = 0; m < 4; ++m) {
        short8 kf = *reinterpret_cast<const short8*>(Kc + (32 + ql) * 64 + ((2 * m + hi) ^ (ql & 7)) * 8);
        s1 = __builtin_amdgcn_mfma_f32_32x32x16_bf16(kf, qf[m], s1, 0, 0, 0);
      }

      // ---- causal mask (diag tile only): kv = kv0 + sub*32 + (r&3)+8*(r>>2)+4*hi
      if (t == nt - 1) {
        const int qg = q0 + ql;
        #pragma unroll
        for (int r = 0; r < 16; ++r) {
          int kvl = (r & 3) + 8 * (r >> 2) + 4 * hi;
          if (kv0 + kvl      > qg) s0[r] = -1e30f;
          if (kv0 + 32 + kvl > qg) s1[r] = -1e30f;
        }
      }

      // ---- online softmax, in-lane (q = ql) + one cross-half shfl
      float mt = s0[0];
      #pragma unroll
      for (int r = 1; r < 16; ++r) mt = fmaxf(mt, s0[r]);
      #pragma unroll
      for (int r = 0; r < 16; ++r) mt = fmaxf(mt, s1[r]);
      mt = fmaxf(mt, __shfl_xor(mt, 32));
      if (__any(mt > m_run + 40.0f)) {           // defer-rescale (raw-units THR = 5/0.125)
        float mnew = fmaxf(m_run, mt);
        float corr = exp2f((m_run - mnew) * SCL2);
        l_run *= corr; m_run = mnew;
        #pragma unroll
        for (int r = 0; r < 16; ++r) {
          float cr = __shfl(corr, (r & 3) + 8 * (r >> 2) + 4 * hi);
          o0[r] *= cr; o1[r] *= cr;
        }
      }
      float ts = 0.f;
      #pragma unroll
      for (int r = 0; r < 16; ++r) {
        s0[r] = exp2f((s0[r] - m_run) * SCL2); ts += s0[r];
        s1[r] = exp2f((s1[r] - m_run) * SCL2); ts += s1[r];
      }
      ts += __shfl_xor(ts, 32);
      l_run += ts;

      // ---- P -> A-fragments in-register, then O += P V
      // chunk kc covers kv [kc*16, kc*16+16); lane needs P[q=ql][kv=kc*16+hi*8+j]
#define PV_CHUNK(SV, CC, KC) do {                                                              \
        unsigned wa = pk2(SV[(CC) * 8 + 0], SV[(CC) * 8 + 1]);                                 \
        unsigned wb = pk2(SV[(CC) * 8 + 2], SV[(CC) * 8 + 3]);                                 \
        unsigned wc = pk2(SV[(CC) * 8 + 4], SV[(CC) * 8 + 5]);                                 \
        unsigned wd = pk2(SV[(CC) * 8 + 6], SV[(CC) * 8 + 7]);                                 \
        unsigned xa = __shfl_xor(wa, 32), xb2 = __shfl_xor(wb, 32);                            \
        unsigned xc = __shfl_xor(wc, 32), xd = __shfl_xor(wd, 32);                             \
        uint4 pw;                                                                              \
        pw.x = hi ? xc : wa;  pw.y = hi ? xd : wb;                                             \
        pw.z = hi ? wc : xa;  pw.w = hi ? wd : xb2;                                            \
        short8 pa = *reinterpret_cast<short8*>(&pw);                                           \
        short8 vf0 = *reinterpret_cast<const short8*>(Vc + ql * 64 +                           \
                       ((2 * (KC) + hi) ^ (ql & 7)) * 8);                                      \
        o0 = __builtin_amdgcn_mfma_f32_32x32x16_bf16(pa, vf0, o0, 0, 0, 0);                    \
        short8 vf1 = *reinterpret_cast<const short8*>(Vc + (32 + ql) * 64 +                    \
                       ((2 * (KC) + hi) ^ (ql & 7)) * 8);                                      \
        o1 = __builtin_amdgcn_mfma_f32_32x32x16_bf16(pa, vf1, o1, 0, 0, 0);                    \
      } while (0)

      PV_CHUNK(s0, 0, 0);
      PV_CHUNK(s0, 1, 1);
      PV_CHUNK(s1, 0, 2);
      PV_CHUNK(s1, 1, 3);
#undef PV_CHUNK
    }

    __syncthreads();
    cur ^= 1;
  }
#undef STAGE

  // ---- epilogue: O[q][e] / l[q], q = q0 + (r&3)+8*(r>>2)+4*hi, e = eh*32+ql
  float rl = 1.0f / l_run;
  #pragma unroll
  for (int r = 0; r < 16; ++r) {
    int base = (r & 3) + 8 * (r >> 2) + 4 * hi;
    float sc_ = __shfl(rl, base);
    int qg = q0 + base;
    float* op = out + ((size_t)b * SQ + qg) * (NH * DH) + h * DH;
    op[ql]      = o0[r] * sc_;
    op[32 + ql] = o1[r] * sc_;
  }
}

extern "C" void kernel_launch(void* const* d_in, const int* in_sizes, int n_in,
                              void* d_out, int out_size, void* d_ws, size_t ws_size,
                              hipStream_t stream) {
  const float* x  = (const float*)d_in[0];
  const float* Wq = (const float*)d_in[1];
  const float* Wk = (const float*)d_in[2];
  const float* Wv = (const float*)d_in[3];
  float* out = (float*)d_out;

  char* ws = (char*)d_ws;
  ushort* xb = (ushort*)(ws);
  ushort* wt = (ushort*)(ws + 12582912);
  ushort* q  = (ushort*)(ws + 16121856);
  ushort* k  = (ushort*)(ws + 28704768);
  ushort* vt = (ushort*)(ws + 41287680);

  k_convert_x<<<6144, 256, 0, stream>>>(x, xb);
  k_prep_w<<<dim3(36, 12), 256, 0, stream>>>(Wq, Wk, Wv, wt);
  k_proj<<<dim3(64, 18), 256, 0, stream>>>(xb, wt, q, k, vt);
  k_attn<<<768, 256, 0, stream>>>(q, k, vt, out);
}